// Round 7
// baseline (238.501 us; speedup 1.0000x reference)
//
#include <hip/hip_runtime.h>

// Problem dims
#define B_SZ 32
#define L_SZ 256
#define D_SZ 512
#define F_SZ 2048
#define E_SZ 8
#define P_SZ 64   // B_SZ * TOP_K
#define BK2  32   // LDS sub-tile K width (two sub-tiles per barrier-pair -> K=64)

typedef __attribute__((ext_vector_type(8)))  short bf16x8;
typedef __attribute__((ext_vector_type(16))) float f32x16;

// f32 -> bf16 round-to-nearest-even (finite inputs only)
__device__ __forceinline__ unsigned short f2bf(float f) {
  unsigned int u = __builtin_bit_cast(unsigned int, f);
  u += 0x7fffu + ((u >> 16) & 1u);
  return (unsigned short)(u >> 16);
}
__device__ __forceinline__ float bf2f(unsigned short s) {
  unsigned int u = ((unsigned int)s) << 16;
  return __builtin_bit_cast(float, u);
}

// async global->LDS, 16B per lane; LDS dest is wave-uniform base + lane*16
__device__ __forceinline__ void async16(const void* g, void* l) {
  __builtin_amdgcn_global_load_lds(
      (const __attribute__((address_space(1))) unsigned int*)g,
      (__attribute__((address_space(3))) unsigned int*)l, 16, 0, 0);
}

// exact gelu via A&S 7.1.26 erf (max abs err ~1.5e-7), fast hw exp/rcp
__device__ __forceinline__ float gelu_f(float x) {
  float a = fabsf(x) * 0.70710678118654752f;
  float t = __builtin_amdgcn_rcpf(1.0f + 0.3275911f * a);
  float y = t * (0.254829592f +
            t * (-0.284496736f +
            t * (1.421413741f +
            t * (-1.453152027f +
            t * 1.061405429f))));
  float e = __expf(-a * a);
  float erf_abs = 1.0f - y * e;
  float erf_v = (x < 0.f) ? -erf_abs : erf_abs;
  return 0.5f * x * (1.0f + erf_v);
}

// LDS-tile transpose+convert helper: 64x64 tile at (r0, c0):
// in [R][C] f32 -> out [C][R] bf16. tile = float[64*65] in LDS.
__device__ __forceinline__ void transpose_tile(
    const float* __restrict__ ip, unsigned short* __restrict__ op,
    int R, int C, int r0, int c0, float* tile, int tid) {
  int tx = tid & 63, ty = tid >> 6;
#pragma unroll
  for (int i = 0; i < 16; ++i) {
    int r = i * 4 + ty;
    tile[r * 65 + tx] = ip[(size_t)(r0 + r) * C + c0 + tx];
  }
  __syncthreads();
#pragma unroll
  for (int uu = 0; uu < 4; ++uu) {
    int u = uu * 256 + tid;
    int cc = u >> 4, q = u & 15;
    ushort4 o;
    o.x = f2bf(tile[(q * 4 + 0) * 65 + cc]);
    o.y = f2bf(tile[(q * 4 + 1) * 65 + cc]);
    o.z = f2bf(tile[(q * 4 + 2) * 65 + cc]);
    o.w = f2bf(tile[(q * 4 + 3) * 65 + cc]);
    *(ushort4*)(op + (size_t)(c0 + cc) * R + r0 + q * 4) = o;
  }
}

// ------------- prep: gates | x->bf16 | W1^T->bf16 ----------------------
#define PREP_CONV_BLKS 4096
#define PREP_TR_BLKS   2048
#define PREP_TOTAL     (1 + PREP_CONV_BLKS + PREP_TR_BLKS)

__global__ __launch_bounds__(256) void prep_kernel(
    const float* __restrict__ logits, const int* __restrict__ masks,
    const float* __restrict__ x,
    const float* __restrict__ W1,
    int* __restrict__ sel_e, float* __restrict__ sel_g,
    unsigned short* __restrict__ xb,
    unsigned short* __restrict__ w1t) {
  __shared__ float tile[64 * 65];
  int blk = blockIdx.x;
  int tid = threadIdx.x;

  if (blk == 0) {
    int b = tid;
    if (b >= B_SZ) return;
    float lg[E_SZ], p[E_SZ];
    float mx = -1e30f;
    for (int e = 0; e < E_SZ; ++e) { lg[e] = logits[b * E_SZ + e]; mx = fmaxf(mx, lg[e]); }
    float s = 0.f;
    for (int e = 0; e < E_SZ; ++e) { p[e] = expf(lg[e] - mx); s += p[e]; }
    for (int e = 0; e < E_SZ; ++e) p[e] = (masks[b * E_SZ + e] == 1) ? (p[e] / s) : 0.f;
    int i0 = 0, i1 = 1; float v0 = -1.f, v1 = -1.f;
    for (int e = 0; e < E_SZ; ++e) {
      float v = p[e];
      if (v > v0)      { v1 = v0; i1 = i0; v0 = v; i0 = e; }
      else if (v > v1) { v1 = v;  i1 = e; }
    }
    float den = v0 + v1 + 1e-9f;
    sel_e[2 * b] = i0;  sel_e[2 * b + 1] = i1;
    sel_g[2 * b] = v0 / den;
    sel_g[2 * b + 1] = v1 / den;
    return;
  }
  blk -= 1;

  if (blk < PREP_CONV_BLKS) {
    int i = blk * 256 + tid;
    float4 v = ((const float4*)x)[i];
    ushort4 o;
    o.x = f2bf(v.x); o.y = f2bf(v.y); o.z = f2bf(v.z); o.w = f2bf(v.w);
    ((ushort4*)xb)[i] = o;
    return;
  }
  blk -= PREP_CONV_BLKS;

  // W1 [E][D][F] -> w1t [E][F][D] : R=D=512 (8 r-tiles), C=F=2048 (32 c-tiles)
  int z = blk >> 8;
  int rem = blk & 255;
  int tr = rem >> 5, tc = rem & 31;
  transpose_tile(W1 + (size_t)z * D_SZ * F_SZ, w1t + (size_t)z * D_SZ * F_SZ,
                 D_SZ, F_SZ, tr * 64, tc * 64, tile, tid);
}

// ------------- stage 1 + backfilled W2 transpose -----------------------
// blocks [0,1024): H[p] = gelu(X_b @ W1[e] + b1[e]).
//   Block tile 128(L) x 256(F); 4 waves as 2M x 2N, wave tile 64x128
//   (2x4 chunks of 32x32). BK=64 via two 32-subtiles; XOR-swizzled LDS.
// blocks [1024,3072): W2 [E][F][D] -> w2t [E][D][F] transpose backfill.
__global__ __launch_bounds__(256, 2) void moe_gemm1(
    const unsigned short* __restrict__ Xb,
    const unsigned short* __restrict__ W1t,
    const float* __restrict__ b1,
    const int* __restrict__ sel_e,
    unsigned short* __restrict__ H,
    const float* __restrict__ W2,
    unsigned short* __restrict__ w2t) {
  __shared__ __align__(16) char smem[49152];
  int tid = threadIdx.x;
  int lin = blockIdx.x;

  if (lin >= 1024) {
    // W2 transpose: R=F=2048 (32 r-tiles), C=D=512 (8 c-tiles)
    int blk = lin - 1024;
    int z = blk >> 8;
    int rem = blk & 255;
    int tr = rem >> 3, tc = rem & 7;
    transpose_tile(W2 + (size_t)z * F_SZ * D_SZ, w2t + (size_t)z * F_SZ * D_SZ,
                   F_SZ, D_SZ, tr * 64, tc * 64, (float*)smem, tid);
    return;
  }

  unsigned short* As = (unsigned short*)smem;            // [2][128*32] 16KB
  unsigned short* Bs = (unsigned short*)(smem + 16384);  // [2][256*32] 32KB

  int f  = lin & 7;
  int l0 = ((lin >> 3) & 1) * 128;
  int p  = lin >> 4;
  int f0 = f * 256;
  int b  = p >> 1;
  int e  = sel_e[p];

  int lane = tid & 63;
  int w = tid >> 6, wm = w & 1, wn = w >> 1;
  int m32 = lane & 31, kh = lane >> 5;
  int sw = (m32 >> 1) & 3;       // read-side XOR swizzle

  const unsigned short* Abase = Xb  + ((size_t)b * L_SZ + l0) * D_SZ;
  const unsigned short* Bbase = W1t + ((size_t)e * F_SZ + f0) * D_SZ;

  // staging: seg (row, slot) fetches global k-chunk slot ^ ((row>>1)&3)
  int arow[2], aks[2], brow[4], bks[4];
#pragma unroll
  for (int c = 0; c < 2; ++c) {
    int seg = c * 256 + tid;
    arow[c] = seg >> 2; aks[c] = ((seg & 3) ^ ((arow[c] >> 1) & 3)) * 8;
  }
#pragma unroll
  for (int c = 0; c < 4; ++c) {
    int seg = c * 256 + tid;
    brow[c] = seg >> 2; bks[c] = ((seg & 3) ^ ((brow[c] >> 1) & 3)) * 8;
  }

  f32x16 acc[2][4] = {};

  for (int k0 = 0; k0 < D_SZ; k0 += 2 * BK2) {
#pragma unroll
    for (int h = 0; h < 2; ++h) {
      int kk = k0 + h * BK2;
#pragma unroll
      for (int c = 0; c < 2; ++c)
        async16(Abase + (size_t)arow[c] * D_SZ + kk + aks[c],
                As + h * 4096 + (c * 256 + tid) * 8);
#pragma unroll
      for (int c = 0; c < 4; ++c)
        async16(Bbase + (size_t)brow[c] * D_SZ + kk + bks[c],
                Bs + h * 8192 + (c * 256 + tid) * 8);
    }
    __syncthreads();
#pragma unroll
    for (int h = 0; h < 2; ++h)
#pragma unroll
      for (int s = 0; s < 2; ++s) {     // K=16 substep
        int ko = (((s << 1) | kh) ^ sw) << 3;
        bf16x8 a[2], bb[4];
#pragma unroll
        for (int i = 0; i < 2; ++i)
          a[i] = *(const bf16x8*)&As[h * 4096 + (wm * 64 + i * 32 + m32) * 32 + ko];
#pragma unroll
        for (int j = 0; j < 4; ++j)
          bb[j] = *(const bf16x8*)&Bs[h * 8192 + (wn * 128 + j * 32 + m32) * 32 + ko];
#pragma unroll
        for (int i = 0; i < 2; ++i)
#pragma unroll
          for (int j = 0; j < 4; ++j)
            acc[i][j] = __builtin_amdgcn_mfma_f32_32x32x16_bf16(a[i], bb[j], acc[i][j], 0, 0, 0);
      }
    __syncthreads();
  }

  // epilogue: +b1, gelu, bf16 direct stores (32 lanes -> 64B contiguous)
  float b1v[4];
#pragma unroll
  for (int j = 0; j < 4; ++j)
    b1v[j] = b1[e * F_SZ + f0 + wn * 128 + j * 32 + m32];

  unsigned short* Hp = H + ((size_t)p * L_SZ + l0) * F_SZ + f0;
#pragma unroll
  for (int i = 0; i < 2; ++i)
#pragma unroll
    for (int j = 0; j < 4; ++j) {
      int col = wn * 128 + j * 32 + m32;
#pragma unroll
      for (int r = 0; r < 16; ++r) {
        int row = wm * 64 + i * 32 + (r & 3) + 8 * (r >> 2) + 4 * kh;
        Hp[(size_t)row * F_SZ + col] = f2bf(gelu_f(acc[i][j][r] + b1v[j]));
      }
    }
}

// ------------- stage 2: slot-split + K-half split, no atomics ----------
// Block tile 128(L) x 256(D), K=1024 per block. Roles (slot parity, kh):
//   (0,0)->part0 bf16, (0,1)->part1 bf16, (1,0)->part2 bf16, (1,1)->Out f32
__global__ __launch_bounds__(256, 2) void moe_gemm2(
    const unsigned short* __restrict__ H,
    const unsigned short* __restrict__ W2t,
    const int* __restrict__ sel_e,
    const float* __restrict__ sel_g,
    unsigned short* __restrict__ part0,
    unsigned short* __restrict__ part1,
    unsigned short* __restrict__ part2,
    float* __restrict__ Out) {
  __shared__ __align__(16) char smem[49152];
  unsigned short* As = (unsigned short*)smem;            // [2][128*32]
  unsigned short* Bs = (unsigned short*)(smem + 16384);  // [2][256*32]

  int lin = blockIdx.x;
  int d   = lin & 1;
  int kq  = (lin >> 1) & 1;
  int l0  = ((lin >> 2) & 1) * 128;
  int p   = lin >> 3;
  int d0  = d * 256;
  int b   = p >> 1;
  int e   = sel_e[p];
  float g = sel_g[p];
  int kbase = kq * (F_SZ / 2);

  int tid = threadIdx.x;
  int lane = tid & 63;
  int w = tid >> 6, wm = w & 1, wn = w >> 1;
  int m32 = lane & 31, kh = lane >> 5;
  int sw = (m32 >> 1) & 3;

  const unsigned short* Abase = H   + ((size_t)p * L_SZ + l0) * F_SZ + kbase;
  const unsigned short* Bbase = W2t + ((size_t)e * D_SZ + d0) * F_SZ + kbase;

  int arow[2], aks[2], brow[4], bks[4];
#pragma unroll
  for (int c = 0; c < 2; ++c) {
    int seg = c * 256 + tid;
    arow[c] = seg >> 2; aks[c] = ((seg & 3) ^ ((arow[c] >> 1) & 3)) * 8;
  }
#pragma unroll
  for (int c = 0; c < 4; ++c) {
    int seg = c * 256 + tid;
    brow[c] = seg >> 2; bks[c] = ((seg & 3) ^ ((brow[c] >> 1) & 3)) * 8;
  }

  f32x16 acc[2][4] = {};

  for (int k0 = 0; k0 < F_SZ / 2; k0 += 2 * BK2) {
#pragma unroll
    for (int h = 0; h < 2; ++h) {
      int kk = k0 + h * BK2;
#pragma unroll
      for (int c = 0; c < 2; ++c)
        async16(Abase + (size_t)arow[c] * F_SZ + kk + aks[c],
                As + h * 4096 + (c * 256 + tid) * 8);
#pragma unroll
      for (int c = 0; c < 4; ++c)
        async16(Bbase + (size_t)brow[c] * F_SZ + kk + bks[c],
                Bs + h * 8192 + (c * 256 + tid) * 8);
    }
    __syncthreads();
#pragma unroll
    for (int h = 0; h < 2; ++h)
#pragma unroll
      for (int s = 0; s < 2; ++s) {
        int ko = (((s << 1) | kh) ^ sw) << 3;
        bf16x8 a[2], bb[4];
#pragma unroll
        for (int i = 0; i < 2; ++i)
          a[i] = *(const bf16x8*)&As[h * 4096 + (wm * 64 + i * 32 + m32) * 32 + ko];
#pragma unroll
        for (int j = 0; j < 4; ++j)
          bb[j] = *(const bf16x8*)&Bs[h * 8192 + (wn * 128 + j * 32 + m32) * 32 + ko];
#pragma unroll
        for (int i = 0; i < 2; ++i)
#pragma unroll
          for (int j = 0; j < 4; ++j)
            acc[i][j] = __builtin_amdgcn_mfma_f32_32x32x16_bf16(a[i], bb[j], acc[i][j], 0, 0, 0);
      }
    __syncthreads();
  }

  // epilogue: gate-scale; role-dependent destination
  int role = (p & 1) * 2 + kq;
  size_t obase = ((size_t)b * L_SZ + l0) * D_SZ + d0;
  if (role == 3) {
    float* Op = Out + obase;
#pragma unroll
    for (int i = 0; i < 2; ++i)
#pragma unroll
      for (int j = 0; j < 4; ++j) {
        int col = wn * 128 + j * 32 + m32;
#pragma unroll
        for (int r = 0; r < 16; ++r) {
          int row = wm * 64 + i * 32 + (r & 3) + 8 * (r >> 2) + 4 * kh;
          Op[(size_t)row * D_SZ + col] = g * acc[i][j][r];
        }
      }
  } else {
    unsigned short* Pp = (role == 0 ? part0 : (role == 1 ? part1 : part2)) + obase;
#pragma unroll
    for (int i = 0; i < 2; ++i)
#pragma unroll
      for (int j = 0; j < 4; ++j) {
        int col = wn * 128 + j * 32 + m32;
#pragma unroll
        for (int r = 0; r < 16; ++r) {
          int row = wm * 64 + i * 32 + (r & 3) + 8 * (r >> 2) + 4 * kh;
          Pp[(size_t)row * D_SZ + col] = f2bf(g * acc[i][j][r]);
        }
      }
  }
}

// ------------- combine: Out += parts + gate-weighted b2 ----------------
__global__ __launch_bounds__(256) void combine_kernel(
    const unsigned short* __restrict__ part0,
    const unsigned short* __restrict__ part1,
    const unsigned short* __restrict__ part2,
    const float* __restrict__ b2,
    const int* __restrict__ sel_e, const float* __restrict__ sel_g,
    float* __restrict__ Out) {
  int i = blockIdx.x * 256 + threadIdx.x;     // over B*L*D/4
  int d4 = i & (D_SZ / 4 - 1);
  int b  = i >> 15;                           // /(L*D/4)
  int e0 = sel_e[2 * b], e1 = sel_e[2 * b + 1];
  float g0 = sel_g[2 * b], g1 = sel_g[2 * b + 1];
  ushort4 p0 = ((const ushort4*)part0)[i];
  ushort4 p1 = ((const ushort4*)part1)[i];
  ushort4 p2 = ((const ushort4*)part2)[i];
  float4 o   = ((float4*)Out)[i];
  float4 v0 = ((const float4*)(b2 + (size_t)e0 * D_SZ))[d4];
  float4 v1 = ((const float4*)(b2 + (size_t)e1 * D_SZ))[d4];
  o.x += bf2f(p0.x) + bf2f(p1.x) + bf2f(p2.x) + g0 * v0.x + g1 * v1.x;
  o.y += bf2f(p0.y) + bf2f(p1.y) + bf2f(p2.y) + g0 * v0.y + g1 * v1.y;
  o.z += bf2f(p0.z) + bf2f(p1.z) + bf2f(p2.z) + g0 * v0.z + g1 * v1.z;
  o.w += bf2f(p0.w) + bf2f(p1.w) + bf2f(p2.w) + g0 * v0.w + g1 * v1.w;
  ((float4*)Out)[i] = o;
}

extern "C" void kernel_launch(void* const* d_in, const int* in_sizes, int n_in,
                              void* d_out, int out_size, void* d_ws, size_t ws_size,
                              hipStream_t stream) {
  const float* x      = (const float*)d_in[0];
  const float* logits = (const float*)d_in[1];
  const int*   masks  = (const int*)d_in[2];
  const float* W1     = (const float*)d_in[3];
  const float* b1     = (const float*)d_in[4];
  const float* W2     = (const float*)d_in[5];
  const float* b2     = (const float*)d_in[6];
  float* out = (float*)d_out;

  // workspace: sel (1K) | xb 8MB | w1t 16MB | w2t 16MB | H 64MB
  // part0/1/2 (bf16, 8MB each = 24MB) alias xb+w1t — dead after gemm1.
  char* ws = (char*)d_ws;
  int*   sel_e = (int*)ws;
  float* sel_g = (float*)(ws + 256);
  unsigned short* xb  = (unsigned short*)(ws + 1024);
  unsigned short* w1t = xb  + (size_t)B_SZ * L_SZ * D_SZ;
  unsigned short* w2t = w1t + (size_t)E_SZ * F_SZ * D_SZ;
  unsigned short* Hbuf = w2t + (size_t)E_SZ * D_SZ * F_SZ;
  unsigned short* part0 = (unsigned short*)(ws + 1024);
  unsigned short* part1 = part0 + (size_t)B_SZ * L_SZ * D_SZ;
  unsigned short* part2 = part1 + (size_t)B_SZ * L_SZ * D_SZ;

  prep_kernel<<<PREP_TOTAL, 256, 0, stream>>>(logits, masks, x, W1,
                                              sel_e, sel_g, xb, w1t);
  moe_gemm1<<<3072, 256, 0, stream>>>(xb, w1t, b1, sel_e, Hbuf, W2, w2t);
  moe_gemm2<<<512, 256, 0, stream>>>(Hbuf, w2t, sel_e, sel_g,
                                     part0, part1, part2, out);
  combine_kernel<<<(B_SZ * L_SZ * D_SZ / 4) / 256, 256, 0, stream>>>(
      part0, part1, part2, b2, sel_e, sel_g, out);
}

// Round 8
// 231.937 us; speedup vs baseline: 1.0283x; 1.0283x over previous
//
#include <hip/hip_runtime.h>

// Problem dims
#define B_SZ 32
#define L_SZ 256
#define D_SZ 512
#define F_SZ 2048
#define E_SZ 8
#define P_SZ 64   // B_SZ * TOP_K
#define BK2  32   // LDS sub-tile K width (two sub-tiles per barrier-pair -> K=64)

typedef __attribute__((ext_vector_type(8)))  short bf16x8;
typedef __attribute__((ext_vector_type(16))) float f32x16;

// f32 -> bf16 round-to-nearest-even (finite inputs only)
__device__ __forceinline__ unsigned short f2bf(float f) {
  unsigned int u = __builtin_bit_cast(unsigned int, f);
  u += 0x7fffu + ((u >> 16) & 1u);
  return (unsigned short)(u >> 16);
}
__device__ __forceinline__ float bf2f(unsigned short s) {
  unsigned int u = ((unsigned int)s) << 16;
  return __builtin_bit_cast(float, u);
}

// async global->LDS, 16B per lane; LDS dest is wave-uniform base + lane*16
__device__ __forceinline__ void async16(const void* g, void* l) {
  __builtin_amdgcn_global_load_lds(
      (const __attribute__((address_space(1))) unsigned int*)g,
      (__attribute__((address_space(3))) unsigned int*)l, 16, 0, 0);
}

// exact gelu via A&S 7.1.26 erf (max abs err ~1.5e-7), fast hw exp/rcp
__device__ __forceinline__ float gelu_f(float x) {
  float a = fabsf(x) * 0.70710678118654752f;
  float t = __builtin_amdgcn_rcpf(1.0f + 0.3275911f * a);
  float y = t * (0.254829592f +
            t * (-0.284496736f +
            t * (1.421413741f +
            t * (-1.453152027f +
            t * 1.061405429f))));
  float e = __expf(-a * a);
  float erf_abs = 1.0f - y * e;
  float erf_v = (x < 0.f) ? -erf_abs : erf_abs;
  return 0.5f * x * (1.0f + erf_v);
}

// LDS-tile transpose+convert helper: 64x64 tile at (r0, c0):
// in [R][C] f32 -> out [C][R] bf16. tile = float[64*65] in LDS.
__device__ __forceinline__ void transpose_tile(
    const float* __restrict__ ip, unsigned short* __restrict__ op,
    int R, int C, int r0, int c0, float* tile, int tid) {
  int tx = tid & 63, ty = tid >> 6;
#pragma unroll
  for (int i = 0; i < 16; ++i) {
    int r = i * 4 + ty;
    tile[r * 65 + tx] = ip[(size_t)(r0 + r) * C + c0 + tx];
  }
  __syncthreads();
#pragma unroll
  for (int uu = 0; uu < 4; ++uu) {
    int u = uu * 256 + tid;
    int cc = u >> 4, q = u & 15;
    ushort4 o;
    o.x = f2bf(tile[(q * 4 + 0) * 65 + cc]);
    o.y = f2bf(tile[(q * 4 + 1) * 65 + cc]);
    o.z = f2bf(tile[(q * 4 + 2) * 65 + cc]);
    o.w = f2bf(tile[(q * 4 + 3) * 65 + cc]);
    *(ushort4*)(op + (size_t)(c0 + cc) * R + r0 + q * 4) = o;
  }
}

// ------------- prep: gates | x->bf16 | W1^T->bf16 ----------------------
#define PREP_CONV_BLKS 4096
#define PREP_TR_BLKS   2048
#define PREP_TOTAL     (1 + PREP_CONV_BLKS + PREP_TR_BLKS)

__global__ __launch_bounds__(256) void prep_kernel(
    const float* __restrict__ logits, const int* __restrict__ masks,
    const float* __restrict__ x,
    const float* __restrict__ W1,
    int* __restrict__ sel_e, float* __restrict__ sel_g,
    unsigned short* __restrict__ xb,
    unsigned short* __restrict__ w1t) {
  __shared__ float tile[64 * 65];
  int blk = blockIdx.x;
  int tid = threadIdx.x;

  if (blk == 0) {
    int b = tid;
    if (b >= B_SZ) return;
    float lg[E_SZ], p[E_SZ];
    float mx = -1e30f;
    for (int e = 0; e < E_SZ; ++e) { lg[e] = logits[b * E_SZ + e]; mx = fmaxf(mx, lg[e]); }
    float s = 0.f;
    for (int e = 0; e < E_SZ; ++e) { p[e] = expf(lg[e] - mx); s += p[e]; }
    for (int e = 0; e < E_SZ; ++e) p[e] = (masks[b * E_SZ + e] == 1) ? (p[e] / s) : 0.f;
    int i0 = 0, i1 = 1; float v0 = -1.f, v1 = -1.f;
    for (int e = 0; e < E_SZ; ++e) {
      float v = p[e];
      if (v > v0)      { v1 = v0; i1 = i0; v0 = v; i0 = e; }
      else if (v > v1) { v1 = v;  i1 = e; }
    }
    float den = v0 + v1 + 1e-9f;
    sel_e[2 * b] = i0;  sel_e[2 * b + 1] = i1;
    sel_g[2 * b] = v0 / den;
    sel_g[2 * b + 1] = v1 / den;
    return;
  }
  blk -= 1;

  if (blk < PREP_CONV_BLKS) {
    int i = blk * 256 + tid;
    float4 v = ((const float4*)x)[i];
    ushort4 o;
    o.x = f2bf(v.x); o.y = f2bf(v.y); o.z = f2bf(v.z); o.w = f2bf(v.w);
    ((ushort4*)xb)[i] = o;
    return;
  }
  blk -= PREP_CONV_BLKS;

  // W1 [E][D][F] -> w1t [E][F][D] : R=D=512 (8 r-tiles), C=F=2048 (32 c-tiles)
  int z = blk >> 8;
  int rem = blk & 255;
  int tr = rem >> 5, tc = rem & 31;
  transpose_tile(W1 + (size_t)z * D_SZ * F_SZ, w1t + (size_t)z * D_SZ * F_SZ,
                 D_SZ, F_SZ, tr * 64, tc * 64, tile, tid);
}

// ------------- stage 1 + backfilled W2 transpose (R6 structure) --------
// blocks [0,2048): H[p] = gelu(X_b @ W1[e] + b1[e]); natural order
//   (f fastest). Both operands via global_load_lds, XOR-swizzled k-chunks;
//   32x32x16 MFMA; two BK=32 sub-tiles per barrier-pair; 4 blocks/CU.
// blocks [2048,4096): W2 [E][F][D] -> w2t [E][D][F] transpose backfill.
__global__ __launch_bounds__(256, 4) void moe_gemm1(
    const unsigned short* __restrict__ Xb,
    const unsigned short* __restrict__ W1t,
    const float* __restrict__ b1,
    const int* __restrict__ sel_e,
    unsigned short* __restrict__ H,
    const float* __restrict__ W2,
    unsigned short* __restrict__ w2t) {
  __shared__ __align__(16) char smem[32768];
  int tid = threadIdx.x;
  int lin = blockIdx.x;

  if (lin >= 2048) {
    // W2 transpose: R=F=2048 (32 r-tiles), C=D=512 (8 c-tiles)
    int blk = lin - 2048;
    int z = blk >> 8;
    int rem = blk & 255;
    int tr = rem >> 3, tc = rem & 7;
    transpose_tile(W2 + (size_t)z * F_SZ * D_SZ, w2t + (size_t)z * F_SZ * D_SZ,
                   F_SZ, D_SZ, tr * 64, tc * 64, (float*)smem, tid);
    return;
  }

  unsigned short* As = (unsigned short*)smem;            // [2][128*BK2]
  unsigned short* Bs = (unsigned short*)(smem + 16384);  // [2][128*BK2]

  int f  = lin & 15;
  int l0 = ((lin >> 4) & 1) * 128;
  int p  = lin >> 5;
  int f0 = f * 128;
  int b  = p >> 1;
  int e  = sel_e[p];

  int lane = tid & 63;
  int w = tid >> 6, wm = w & 1, wn = w >> 1;
  int m32 = lane & 31, kh = lane >> 5;
  int sw = (m32 >> 1) & 3;       // read-side XOR swizzle

  const unsigned short* Abase = Xb  + ((size_t)b * L_SZ + l0) * D_SZ;
  const unsigned short* Bbase = W1t + ((size_t)e * F_SZ + f0) * D_SZ;

  // staging: seg (row, slot) fetches global k-chunk slot ^ ((row>>1)&3)
  int seg0 = w * 128 + lane;
  int row0 = seg0 >> 2, ks0 = ((seg0 & 3) ^ ((row0 >> 1) & 3)) * 8;
  int seg1 = seg0 + 64;
  int row1 = seg1 >> 2, ks1 = ((seg1 & 3) ^ ((row1 >> 1) & 3)) * 8;

  f32x16 acc[2][2] = {};

  for (int k0 = 0; k0 < D_SZ; k0 += 2 * BK2) {
#pragma unroll
    for (int h = 0; h < 2; ++h) {
      int kk = k0 + h * BK2;
      async16(Abase + (size_t)row0 * D_SZ + kk + ks0, &As[(h * 512 + seg0) * 8]);
      async16(Abase + (size_t)row1 * D_SZ + kk + ks1, &As[(h * 512 + seg1) * 8]);
      async16(Bbase + (size_t)row0 * D_SZ + kk + ks0, &Bs[(h * 512 + seg0) * 8]);
      async16(Bbase + (size_t)row1 * D_SZ + kk + ks1, &Bs[(h * 512 + seg1) * 8]);
    }
    __syncthreads();
#pragma unroll
    for (int h = 0; h < 2; ++h)
#pragma unroll
      for (int s = 0; s < 2; ++s) {     // K=16 substep
        int ko = ((((s << 1) | kh) ^ sw) << 3) + h * 4096;
        bf16x8 a0  = *(const bf16x8*)&As[(wm * 64 +      m32) * BK2 + ko];
        bf16x8 a1  = *(const bf16x8*)&As[(wm * 64 + 32 + m32) * BK2 + ko];
        bf16x8 b0  = *(const bf16x8*)&Bs[(wn * 64 +      m32) * BK2 + ko];
        bf16x8 b1f = *(const bf16x8*)&Bs[(wn * 64 + 32 + m32) * BK2 + ko];
        acc[0][0] = __builtin_amdgcn_mfma_f32_32x32x16_bf16(a0, b0,  acc[0][0], 0, 0, 0);
        acc[0][1] = __builtin_amdgcn_mfma_f32_32x32x16_bf16(a0, b1f, acc[0][1], 0, 0, 0);
        acc[1][0] = __builtin_amdgcn_mfma_f32_32x32x16_bf16(a1, b0,  acc[1][0], 0, 0, 0);
        acc[1][1] = __builtin_amdgcn_mfma_f32_32x32x16_bf16(a1, b1f, acc[1][1], 0, 0, 0);
      }
    __syncthreads();
  }

  // epilogue: +b1, gelu, bf16 direct stores (32 lanes -> 64B contiguous)
  float b1v[2];
#pragma unroll
  for (int tj = 0; tj < 2; ++tj)
    b1v[tj] = b1[e * F_SZ + f0 + wn * 64 + tj * 32 + m32];

  unsigned short* Hp = H + ((size_t)p * L_SZ + l0) * F_SZ + f0;
#pragma unroll
  for (int ti = 0; ti < 2; ++ti)
#pragma unroll
    for (int tj = 0; tj < 2; ++tj) {
      int col = wn * 64 + tj * 32 + m32;
#pragma unroll
      for (int r = 0; r < 16; ++r) {
        int row = wm * 64 + ti * 32 + (r & 3) + 8 * (r >> 2) + 4 * kh;
        Hp[(size_t)row * F_SZ + col] = f2bf(gelu_f(acc[ti][tj][r] + b1v[tj]));
      }
    }
}

// ------------- stage 2: slot-split + K-half split, no atomics ----------
// 128x128 tile, K=1024 per block, 1024 blocks = 4 blocks/CU.
// Roles (slot parity, K-half): (0,0)->part0 bf16, (0,1)->part1 bf16,
//   (1,0)->part2 bf16, (1,1)->Out f32 (bias added in combine).
__global__ __launch_bounds__(256, 4) void moe_gemm2(
    const unsigned short* __restrict__ H,
    const unsigned short* __restrict__ W2t,
    const int* __restrict__ sel_e,
    const float* __restrict__ sel_g,
    unsigned short* __restrict__ part0,
    unsigned short* __restrict__ part1,
    unsigned short* __restrict__ part2,
    float* __restrict__ Out) {
  __shared__ __align__(16) unsigned short As[2][128 * BK2];
  __shared__ __align__(16) unsigned short Bs[2][128 * BK2];

  int lin = blockIdx.x;
  int kq  = lin >> 9;            // K-half
  int l9  = lin & 511;
  int q   = l9 & 7;
  int d   = (l9 >> 3) & 3;
  int g8  = l9 >> 5;
  int gg  = g8 * 8 + q;          // (p, l-tile), 0..127 — same XCD across d
  int p   = gg >> 1;
  int l0  = (gg & 1) * 128;
  int d0  = d * 128;
  int b   = p >> 1;
  int e   = sel_e[p];
  float g = sel_g[p];
  int kbase = kq * (F_SZ / 2);

  int tid = threadIdx.x;
  int lane = tid & 63;
  int w = tid >> 6, wm = w & 1, wn = w >> 1;
  int m32 = lane & 31, kh = lane >> 5;
  int sw = (m32 >> 1) & 3;

  const unsigned short* Abase = H   + ((size_t)p * L_SZ + l0) * F_SZ + kbase;
  const unsigned short* Bbase = W2t + ((size_t)e * D_SZ + d0) * F_SZ + kbase;

  int seg0 = w * 128 + lane;
  int row0 = seg0 >> 2, ks0 = ((seg0 & 3) ^ ((row0 >> 1) & 3)) * 8;
  int seg1 = seg0 + 64;
  int row1 = seg1 >> 2, ks1 = ((seg1 & 3) ^ ((row1 >> 1) & 3)) * 8;

  f32x16 acc[2][2] = {};

  for (int k0 = 0; k0 < F_SZ / 2; k0 += 2 * BK2) {
#pragma unroll
    for (int h = 0; h < 2; ++h) {
      int kk = k0 + h * BK2;
      async16(Abase + (size_t)row0 * F_SZ + kk + ks0, &As[h][seg0 * 8]);
      async16(Abase + (size_t)row1 * F_SZ + kk + ks1, &As[h][seg1 * 8]);
      async16(Bbase + (size_t)row0 * F_SZ + kk + ks0, &Bs[h][seg0 * 8]);
      async16(Bbase + (size_t)row1 * F_SZ + kk + ks1, &Bs[h][seg1 * 8]);
    }
    __syncthreads();
#pragma unroll
    for (int h = 0; h < 2; ++h)
#pragma unroll
      for (int s = 0; s < 2; ++s) {
        int ko = (((s << 1) | kh) ^ sw) << 3;
        bf16x8 a0  = *(const bf16x8*)&As[h][(wm * 64 +      m32) * BK2 + ko];
        bf16x8 a1  = *(const bf16x8*)&As[h][(wm * 64 + 32 + m32) * BK2 + ko];
        bf16x8 b0  = *(const bf16x8*)&Bs[h][(wn * 64 +      m32) * BK2 + ko];
        bf16x8 b1f = *(const bf16x8*)&Bs[h][(wn * 64 + 32 + m32) * BK2 + ko];
        acc[0][0] = __builtin_amdgcn_mfma_f32_32x32x16_bf16(a0, b0,  acc[0][0], 0, 0, 0);
        acc[0][1] = __builtin_amdgcn_mfma_f32_32x32x16_bf16(a0, b1f, acc[0][1], 0, 0, 0);
        acc[1][0] = __builtin_amdgcn_mfma_f32_32x32x16_bf16(a1, b0,  acc[1][0], 0, 0, 0);
        acc[1][1] = __builtin_amdgcn_mfma_f32_32x32x16_bf16(a1, b1f, acc[1][1], 0, 0, 0);
      }
    __syncthreads();
  }

  // epilogue: gate-scale; role-dependent destination, direct stores
  int role = (p & 1) * 2 + kq;
  size_t obase = ((size_t)b * L_SZ + l0) * D_SZ + d0;
  if (role == 3) {
    float* Op = Out + obase;
#pragma unroll
    for (int ti = 0; ti < 2; ++ti)
#pragma unroll
      for (int tj = 0; tj < 2; ++tj) {
        int col = wn * 64 + tj * 32 + m32;
#pragma unroll
        for (int r = 0; r < 16; ++r) {
          int row = wm * 64 + ti * 32 + (r & 3) + 8 * (r >> 2) + 4 * kh;
          Op[(size_t)row * D_SZ + col] = g * acc[ti][tj][r];
        }
      }
  } else {
    unsigned short* Pp =
        (role == 0 ? part0 : (role == 1 ? part1 : part2)) + obase;
#pragma unroll
    for (int ti = 0; ti < 2; ++ti)
#pragma unroll
      for (int tj = 0; tj < 2; ++tj) {
        int col = wn * 64 + tj * 32 + m32;
#pragma unroll
        for (int r = 0; r < 16; ++r) {
          int row = wm * 64 + ti * 32 + (r & 3) + 8 * (r >> 2) + 4 * kh;
          Pp[(size_t)row * D_SZ + col] = f2bf(g * acc[ti][tj][r]);
        }
      }
  }
}

// ------------- combine: Out += parts + gate-weighted b2 ----------------
__global__ __launch_bounds__(256) void combine_kernel(
    const unsigned short* __restrict__ part0,
    const unsigned short* __restrict__ part1,
    const unsigned short* __restrict__ part2,
    const float* __restrict__ b2,
    const int* __restrict__ sel_e, const float* __restrict__ sel_g,
    float* __restrict__ Out) {
  int i = blockIdx.x * 256 + threadIdx.x;     // over B*L*D/4
  int d4 = i & (D_SZ / 4 - 1);
  int b  = i >> 15;                           // /(L*D/4)
  int e0 = sel_e[2 * b], e1 = sel_e[2 * b + 1];
  float g0 = sel_g[2 * b], g1 = sel_g[2 * b + 1];
  ushort4 p0 = ((const ushort4*)part0)[i];
  ushort4 p1 = ((const ushort4*)part1)[i];
  ushort4 p2 = ((const ushort4*)part2)[i];
  float4 o   = ((float4*)Out)[i];
  float4 v0 = ((const float4*)(b2 + (size_t)e0 * D_SZ))[d4];
  float4 v1 = ((const float4*)(b2 + (size_t)e1 * D_SZ))[d4];
  o.x += bf2f(p0.x) + bf2f(p1.x) + bf2f(p2.x) + g0 * v0.x + g1 * v1.x;
  o.y += bf2f(p0.y) + bf2f(p1.y) + bf2f(p2.y) + g0 * v0.y + g1 * v1.y;
  o.z += bf2f(p0.z) + bf2f(p1.z) + bf2f(p2.z) + g0 * v0.z + g1 * v1.z;
  o.w += bf2f(p0.w) + bf2f(p1.w) + bf2f(p2.w) + g0 * v0.w + g1 * v1.w;
  ((float4*)Out)[i] = o;
}

extern "C" void kernel_launch(void* const* d_in, const int* in_sizes, int n_in,
                              void* d_out, int out_size, void* d_ws, size_t ws_size,
                              hipStream_t stream) {
  const float* x      = (const float*)d_in[0];
  const float* logits = (const float*)d_in[1];
  const int*   masks  = (const int*)d_in[2];
  const float* W1     = (const float*)d_in[3];
  const float* b1     = (const float*)d_in[4];
  const float* W2     = (const float*)d_in[5];
  const float* b2     = (const float*)d_in[6];
  float* out = (float*)d_out;

  // workspace: sel (1K) | xb 8.4MB | w1t 16.8MB | w2t 16.8MB | H 67MB
  // part0/1/2 (bf16, 8.4MB each) alias xb+w1t — dead after gemm1.
  char* ws = (char*)d_ws;
  int*   sel_e = (int*)ws;
  float* sel_g = (float*)(ws + 256);
  unsigned short* xb  = (unsigned short*)(ws + 1024);
  unsigned short* w1t = xb  + (size_t)B_SZ * L_SZ * D_SZ;
  unsigned short* w2t = w1t + (size_t)E_SZ * F_SZ * D_SZ;
  unsigned short* Hbuf = w2t + (size_t)E_SZ * D_SZ * F_SZ;
  unsigned short* part0 = (unsigned short*)(ws + 1024);
  unsigned short* part1 = part0 + (size_t)B_SZ * L_SZ * D_SZ;
  unsigned short* part2 = part1 + (size_t)B_SZ * L_SZ * D_SZ;

  prep_kernel<<<PREP_TOTAL, 256, 0, stream>>>(logits, masks, x, W1,
                                              sel_e, sel_g, xb, w1t);
  moe_gemm1<<<4096, 256, 0, stream>>>(xb, w1t, b1, sel_e, Hbuf, W2, w2t);
  moe_gemm2<<<1024, 256, 0, stream>>>(Hbuf, w2t, sel_e, sel_g,
                                      part0, part1, part2, out);
  combine_kernel<<<(B_SZ * L_SZ * D_SZ / 4) / 256, 256, 0, stream>>>(
      part0, part1, part2, b2, sel_e, sel_g, out);
}